// Round 8
// baseline (122.585 us; speedup 1.0000x reference)
//
#include <hip/hip_runtime.h>
#include <math.h>

typedef __bf16 bf16;
typedef __attribute__((ext_vector_type(8))) __bf16 bf16x8;
typedef __attribute__((ext_vector_type(4))) __bf16 bf16x4;
typedef __attribute__((ext_vector_type(4))) float f32x4;

#define MFMA(a, b, c) __builtin_amdgcn_mfma_f32_16x16x32_bf16((a), (b), (c), 0, 0, 0)
#define BARR() __builtin_amdgcn_s_barrier()
#define SFEN() __builtin_amdgcn_sched_barrier(0)
#define WAITV(n) asm volatile("s_waitcnt vmcnt(" #n ")" ::: "memory")

static constexpr int NB = 16384;   // batch
static constexpr int NC = 512;     // feature dim
static constexpr int NH = 128;     // bottleneck
static constexpr int ND = 3;       // domains
static constexpr int NT = 1380;    // text rows
static constexpr int NTP = 1408;   // padded to 128
static constexpr int NTILE = 131;  // max 128-row packed tiles
static constexpr int NPMAX = NTILE * 128;

__device__ __forceinline__ void gld16(const bf16* g, void* l) {
  __builtin_amdgcn_global_load_lds(
      (const __attribute__((address_space(1))) void*)g,
      (__attribute__((address_space(3))) void*)l, 16, 0, 0);
}

// ---------------------------------------------------------------------------
// prep: text row-normalize -> bf16; W1/W2 transpose via coalesced 64x64 LDS
// tile transpose (old version did stride-512B scalar reads = 16x line waste);
// X f32 -> bf16.
// block ids: [0,NTP) text | [NTP,NTP+48) W1 | [+48,+96) W2 | [+96,+96+2048) X
// ---------------------------------------------------------------------------
__global__ __launch_bounds__(64) void k_prep(
    const float* __restrict__ X, const float* __restrict__ W1,
    const float* __restrict__ W2, const float* __restrict__ txt,
    bf16* __restrict__ Xbf, bf16* __restrict__ W1t,
    bf16* __restrict__ W2t, bf16* __restrict__ Tbf)
{
  __shared__ float tl[64][65];
  const int b = blockIdx.x, t = threadIdx.x;
  if (b < NTP) {
    bf16x4* dst = (bf16x4*)(Tbf + (size_t)b * NC);
    if (b < NT) {
      const float4* src = (const float4*)(txt + (size_t)b * NC);
      float4 u0 = src[t * 2], u1 = src[t * 2 + 1];
      float ssq = u0.x * u0.x + u0.y * u0.y + u0.z * u0.z + u0.w * u0.w +
                  u1.x * u1.x + u1.y * u1.y + u1.z * u1.z + u1.w * u1.w;
      for (int m = 32; m; m >>= 1) ssq += __shfl_xor(ssq, m, 64);
      float inv = 1.0f / sqrtf(ssq);
      bf16x4 o0 = {(bf16)(u0.x * inv), (bf16)(u0.y * inv), (bf16)(u0.z * inv), (bf16)(u0.w * inv)};
      bf16x4 o1 = {(bf16)(u1.x * inv), (bf16)(u1.y * inv), (bf16)(u1.z * inv), (bf16)(u1.w * inv)};
      dst[t * 2] = o0; dst[t * 2 + 1] = o1;
    } else {
      bf16x4 z = {(bf16)0.f, (bf16)0.f, (bf16)0.f, (bf16)0.f};
      dst[t * 2] = z; dst[t * 2 + 1] = z;
    }
  } else if (b < NTP + 48) {
    // W1 [d][512][128] -> W1t[d][n][i]; tile (i0,n0) 64x64
    const int e = b - NTP, d = e >> 4, rem = e & 15;
    const int i0 = (rem >> 1) * 64, n0 = (rem & 1) * 64;
    const float* src = W1 + (size_t)d * NC * NH;
    for (int r = 0; r < 64; ++r) tl[r][t] = src[(size_t)(i0 + r) * NH + n0 + t];
    __syncthreads();
    bf16* dst = W1t + (size_t)d * NH * NC;
    for (int r = 0; r < 64; ++r)
      dst[(size_t)(n0 + r) * NC + i0 + t] = (bf16)tl[t][r];
  } else if (b < NTP + 96) {
    // W2 [d][128][512] -> W2t[d][n][j]; tile (j0,n0) 64x64
    const int e = b - (NTP + 48), d = e >> 4, rem = e & 15;
    const int j0 = (rem >> 3) * 64, n0 = (rem & 7) * 64;
    const float* src = W2 + (size_t)d * NH * NC;
    for (int r = 0; r < 64; ++r) tl[r][t] = src[(size_t)(j0 + r) * NC + n0 + t];
    __syncthreads();
    bf16* dst = W2t + (size_t)d * NC * NH;
    for (int r = 0; r < 64; ++r)
      dst[(size_t)(n0 + r) * NH + j0 + t] = (bf16)tl[t][r];
  } else {
    const int id = b - (NTP + 96);                    // 0..2047
    const float4* src = (const float4*)X;
    bf16x4* dst = (bf16x4*)Xbf;
    const size_t base = (size_t)id * 1024 + (size_t)t * 16;
    for (int i = 0; i < 16; ++i) {
      float4 u = src[base + i];
      bf16x4 o = {(bf16)u.x, (bf16)u.y, (bf16)u.z, (bf16)u.w};
      dst[base + i] = o;
    }
  }
}

// ---------------------------------------------------------------------------
// k_sort: deterministic counting sort of rows by domain into padded,
// 128-aligned segments. One block, 1024 threads, 16 rows/thread.
// ---------------------------------------------------------------------------
__global__ __launch_bounds__(1024) void k_sort(
    const int* __restrict__ lab, int* __restrict__ map, int* __restrict__ dmeta)
{
  __shared__ int woff[16][3];
  __shared__ int segbase[4];
  __shared__ int padded[3];
  const int t = threadIdx.x, lane = t & 63, wv = t >> 6;
  int c[3] = {0, 0, 0};
  int ld[16];
  const int base = t * 16;
#pragma unroll
  for (int i = 0; i < 16; ++i) { ld[i] = lab[base + i]; c[ld[i]]++; }
  int exc[3];
#pragma unroll
  for (int d = 0; d < 3; ++d) {
    int v = c[d];
    for (int off = 1; off < 64; off <<= 1) {
      int u = __shfl_up(v, off, 64);
      if (lane >= off) v += u;
    }
    exc[d] = v - c[d];
    if (lane == 63) woff[wv][d] = v;
  }
  __syncthreads();
  if (t == 0) {
    int tot[3] = {0, 0, 0};
    for (int w = 0; w < 16; ++w)
      for (int d = 0; d < 3; ++d) { int v = woff[w][d]; woff[w][d] = tot[d]; tot[d] += v; }
    int s = 0;
    for (int d = 0; d < 3; ++d) {
      padded[d] = (tot[d] + 127) & ~127;
      segbase[d] = s; s += padded[d];
    }
    segbase[3] = s;
    dmeta[NTILE] = s;
  }
  __syncthreads();
  for (int tile = t; tile < NTILE; tile += 1024) {
    const int slot = tile * 128;
    int dd = -1;
    for (int d = 0; d < 3; ++d)
      if (slot >= segbase[d] && slot < segbase[d] + padded[d]) dd = d;
    dmeta[tile] = dd;
  }
  for (int i = t; i < NPMAX; i += 1024) map[i] = -1;
  __syncthreads();
  int pos[3];
#pragma unroll
  for (int d = 0; d < 3; ++d) pos[d] = segbase[d] + woff[wv][d] + exc[d];
#pragma unroll
  for (int i = 0; i < 16; ++i) { int d = ld[i]; map[pos[d]++] = base + i; }
}

// ---------------------------------------------------------------------------
// Fragment-read + 16-MFMA cluster (BK=32, 64B LDS rows, verified 0-conflict
// swizzle). No setprio (m190: negative on lockstep GEMM).
// ---------------------------------------------------------------------------
__device__ __forceinline__ void ctile32(const bf16* As_, const bf16* Bs_,
                                        int ra, int rb, int lr, int lg,
                                        f32x4 (*acc)[4]) {
  bf16x8 a[4], b[4];
#pragma unroll
  for (int m = 0; m < 4; ++m) {
    const int r = ra + m * 16 + lr;
    a[m] = *(const bf16x8*)&As_[r * 32 + ((lg * 8) ^ (((r >> 1) & 3) << 3))];
  }
#pragma unroll
  for (int n = 0; n < 4; ++n) {
    const int r = rb + n * 16 + lr;
    b[n] = *(const bf16x8*)&Bs_[r * 32 + ((lg * 8) ^ (((r >> 1) & 3) << 3))];
  }
#pragma unroll
  for (int m = 0; m < 4; ++m)
#pragma unroll
    for (int n = 0; n < 4; ++n)
      acc[m][n] = MFMA(a[m], b[n], acc[m][n]);
}

// ---------------------------------------------------------------------------
// gemm3: out = exp(logit_scale) * feats @ txt^T   [16384 x 1380] f32
// grid (64, 11) x 512 thr (8 waves, 4Mx2N). 256x128 tile, BK=32, 2-buffer
// counted-vmcnt schedule (R5-gemm1-proven barrier discipline): 16 MFMA/wave
// per interval (2x the 128^2 tile), 44 intervals/CU (vs 88), 48 KiB LDS ->
// 2 blocks/CU for cross-block drain overlap.
// ---------------------------------------------------------------------------
__global__ __launch_bounds__(512) void k_gemm3(
    const bf16* __restrict__ Fbf, const bf16* __restrict__ Tbf,
    const float* __restrict__ lsc, float* __restrict__ out)
{
  __shared__ bf16 As[2][256 * 32];
  __shared__ bf16 Bs[2][128 * 32];
  const int bx = blockIdx.x, by = blockIdx.y;
  const int t = threadIdx.x, w = t >> 6, l = t & 63;
  const int wr = w >> 1, wc = w & 1;           // 4 x 2 waves
  const int lr = l & 15, lg = l >> 4;
  const int row0 = bx * 256, col0 = by * 128;
  const bf16* Ag = Fbf + (size_t)row0 * NC;
  const bf16* Bg = Tbf + (size_t)col0 * NC;

  // A: 2 chunks (16 KiB), B: 1 chunk (8 KiB); 3 gld16/thread per K-tile
#define STG3(buf, kt)                                                         \
  {                                                                           \
    _Pragma("unroll")                                                         \
    for (int i = 0; i < 2; ++i) {                                             \
      const int off = (i * 512 + t) * 16;                                     \
      const int row = off >> 6;                                               \
      const int src = (off & 63) ^ (((row >> 1) & 3) << 4);                   \
      gld16(Ag + (size_t)row * NC + (size_t)(kt) * 32 + (src >> 1),           \
            (char*)As[buf] + off);                                            \
    }                                                                         \
    {                                                                         \
      const int off = t * 16;                                                 \
      const int row = off >> 6;                                               \
      const int src = (off & 63) ^ (((row >> 1) & 3) << 4);                   \
      gld16(Bg + (size_t)row * NC + (size_t)(kt) * 32 + (src >> 1),           \
            (char*)Bs[buf] + off);                                            \
    }                                                                         \
  }

  f32x4 acc[4][4] = {};
  STG3(0, 0); STG3(1, 1);                      // 6 outstanding
#pragma unroll 1
  for (int ks = 0; ks < 14; ++ks) {
    const int cur = ks & 1;
    WAITV(3); BARR(); SFEN();                  // tile ks landed (own-wave count)
    ctile32(As[cur], Bs[cur], wr * 64, wc * 64, lr, lg, acc);
    BARR(); SFEN();                            // all waves done reading buf cur
    STG3(cur, ks + 2);                         // refill freed buffer
  }
  WAITV(3); BARR(); SFEN();
  ctile32(As[0], Bs[0], wr * 64, wc * 64, lr, lg, acc);   // ks=14
  WAITV(0); BARR(); SFEN();
  ctile32(As[1], Bs[1], wr * 64, wc * 64, lr, lg, acc);   // ks=15

  const float s = expf(lsc[0]);
#pragma unroll
  for (int m = 0; m < 4; ++m)
#pragma unroll
    for (int n = 0; n < 4; ++n)
#pragma unroll
      for (int r = 0; r < 4; ++r) {
        const int row = row0 + wr * 64 + m * 16 + lg * 4 + r;
        const int col = col0 + wc * 64 + n * 16 + lr;
        if (col < NT) out[(size_t)row * NT + col] = s * acc[m][n][r];
      }
#undef STG3
}

// ---------------------------------------------------------------------------
// gemm1 (routed): Hp[slot] = relu(X[map[slot]] @ W1[dom])   (R5 version)
// grid 2*NTILE x 256. 64x128 tile, BK=64, depth-2 counted-vmcnt pipeline.
// ---------------------------------------------------------------------------
template <int MF>
__device__ __forceinline__ void ctile(const bf16* As_, const bf16* Bs_,
                                      int ra, int rb, int lr, int lg,
                                      f32x4 (*acc)[4]) {
#pragma unroll
  for (int ks = 0; ks < 2; ++ks) {
    const int colb = ks * 64 + lg * 16;
    bf16x8 a[MF], b[4];
#pragma unroll
    for (int m = 0; m < MF; ++m) {
      const int r = ra + m * 16 + lr;
      a[m] = *(const bf16x8*)((const char*)As_ + r * 128 + (colb ^ ((r & 7) << 4)));
    }
#pragma unroll
    for (int n = 0; n < 4; ++n) {
      const int r = rb + n * 16 + lr;
      b[n] = *(const bf16x8*)((const char*)Bs_ + r * 128 + (colb ^ ((r & 7) << 4)));
    }
    __builtin_amdgcn_s_setprio(1);
#pragma unroll
    for (int m = 0; m < MF; ++m)
#pragma unroll
      for (int n = 0; n < 4; ++n)
        acc[m][n] = MFMA(a[m], b[n], acc[m][n]);
    __builtin_amdgcn_s_setprio(0);
  }
}

__global__ __launch_bounds__(256) void k_gemm1(
    const bf16* __restrict__ Xbf, const bf16* __restrict__ W1t,
    const int* __restrict__ map, const int* __restrict__ dmeta,
    bf16* __restrict__ Hp)
{
  __shared__ bf16 As[2][64 * 64];
  __shared__ bf16 Bs[2][128 * 64];
  const int bx = blockIdx.x;
  int d = dmeta[bx >> 1]; if (d < 0) d = 0;
  const int t = threadIdx.x, w = t >> 6, l = t & 63;
  const int wr = w >> 1, wc = w & 1;
  const int lr = l & 15, lg = l >> 4;
  const int row0 = bx * 64;
  const bf16* Bg = W1t + (size_t)d * NH * NC;

  int g0 = map[row0 + (t >> 3)];          if (g0 < 0) g0 = 0;
  int g1 = map[row0 + 32 + (t >> 3)];     if (g1 < 0) g1 = 0;
  const int arow[2] = {g0, g1};
  int srow[4], scol[4];
#pragma unroll
  for (int i = 0; i < 4; ++i) {
    const int off = i * 4096 + t * 16;
    srow[i] = off >> 7;
    scol[i] = ((off & 127) ^ ((srow[i] & 7) << 4)) >> 1;
  }
#define STG1(buf, kt)                                                         \
  {                                                                           \
    _Pragma("unroll")                                                         \
    for (int i = 0; i < 2; ++i) {                                             \
      const int off = i * 4096 + t * 16;                                      \
      gld16(Xbf + (size_t)arow[i] * NC + (kt) * 64 + scol[i],                 \
            (char*)As[buf] + off);                                            \
    }                                                                         \
    _Pragma("unroll")                                                         \
    for (int i = 0; i < 4; ++i) {                                             \
      const int off = i * 4096 + t * 16;                                      \
      gld16(Bg + (size_t)srow[i] * NC + (kt) * 64 + scol[i],                  \
            (char*)Bs[buf] + off);                                            \
    }                                                                         \
  }

  f32x4 acc[2][4] = {};
  STG1(0, 0); STG1(1, 1);
#pragma unroll 1
  for (int it = 0; it < 3; ++it) {
    WAITV(6); BARR(); SFEN();
    ctile<2>(As[0], Bs[0], wr * 32, wc * 64, lr, lg, acc);
    BARR(); SFEN();
    STG1(0, 2 * it + 2);
    WAITV(6); BARR(); SFEN();
    ctile<2>(As[1], Bs[1], wr * 32, wc * 64, lr, lg, acc);
    BARR(); SFEN();
    STG1(1, 2 * it + 3);
  }
  WAITV(6); BARR(); SFEN();
  ctile<2>(As[0], Bs[0], wr * 32, wc * 64, lr, lg, acc);
  WAITV(0); BARR(); SFEN();
  ctile<2>(As[1], Bs[1], wr * 32, wc * 64, lr, lg, acc);

#pragma unroll
  for (int m = 0; m < 2; ++m)
#pragma unroll
    for (int n = 0; n < 4; ++n)
#pragma unroll
      for (int r = 0; r < 4; ++r) {
        const int row = row0 + wr * 32 + m * 16 + lg * 4 + r;
        const int col = wc * 64 + n * 16 + lr;
        float v = acc[m][n][r];
        Hp[(size_t)row * NH + col] = (bf16)(v > 0.f ? v : 0.f);
      }
#undef STG1
}

// ---------------------------------------------------------------------------
// gemm2 (routed): a = relu(Hp @ W2[dom]), blend with X[map], row-normalize,
// scatter to Fbf[map]. grid 2*NTILE x 512.  (R5 version)
// ---------------------------------------------------------------------------
__global__ __launch_bounds__(512) void k_gemm2(
    const bf16* __restrict__ Hp, const bf16* __restrict__ W2t,
    const bf16* __restrict__ Xbf, const int* __restrict__ map,
    const int* __restrict__ dmeta, bf16* __restrict__ Fbf)
{
  __shared__ float rssq[8][64];
  __shared__ int smap[64];
  const int bx = blockIdx.x;
  const int d = dmeta[bx >> 1];
  if (d < 0) return;
  const int t = threadIdx.x, w = t >> 6, l = t & 63;
  const int lr = l & 15, lg = l >> 4;
  const int row0 = bx * 64;
  const int col0 = w * 64;
  if (t < 64) smap[t] = map[row0 + t];
  __syncthreads();

  f32x4 acc[4][4] = {};
  const bf16* A = Hp + (size_t)row0 * NH;
  const bf16* Bm = W2t + ((size_t)d * NC + col0) * NH;
  for (int ks = 0; ks < 4; ++ks) {
    const int k0 = ks * 32 + lg * 8;
    bf16x8 a[4], bq[4];
#pragma unroll
    for (int m = 0; m < 4; ++m) a[m]  = *(const bf16x8*)(A  + (size_t)(m * 16 + lr) * NH + k0);
#pragma unroll
    for (int n = 0; n < 4; ++n) bq[n] = *(const bf16x8*)(Bm + (size_t)(n * 16 + lr) * NH + k0);
#pragma unroll
    for (int m = 0; m < 4; ++m)
#pragma unroll
      for (int n = 0; n < 4; ++n)
        acc[m][n] = MFMA(a[m], bq[n], acc[m][n]);
  }

#pragma unroll
  for (int m = 0; m < 4; ++m)
#pragma unroll
    for (int r = 0; r < 4; ++r) {
      const int rl = m * 16 + lg * 4 + r;
      const int grow = smap[rl];
      const size_t row = grow < 0 ? 0 : (size_t)grow;
      float part = 0.f;
#pragma unroll
      for (int n = 0; n < 4; ++n) {
        const int col = col0 + n * 16 + lr;
        float v = acc[m][n][r];
        v = v > 0.f ? v : 0.f;
        v = 0.2f * v + 0.8f * (float)Xbf[row * NC + col];
        acc[m][n][r] = v;
        part += v * v;
      }
      part += __shfl_xor(part, 1, 64);
      part += __shfl_xor(part, 2, 64);
      part += __shfl_xor(part, 4, 64);
      part += __shfl_xor(part, 8, 64);
      if (lr == 0) rssq[w][rl] = part;
    }
  __syncthreads();
#pragma unroll
  for (int m = 0; m < 4; ++m)
#pragma unroll
    for (int r = 0; r < 4; ++r) {
      const int rl = m * 16 + lg * 4 + r;
      const int grow = smap[rl];
      if (grow < 0) continue;
      float tot = 0.f;
#pragma unroll
      for (int ww = 0; ww < 8; ++ww) tot += rssq[ww][rl];
      const float inv = 1.0f / sqrtf(tot);
#pragma unroll
      for (int n = 0; n < 4; ++n) {
        const int col = col0 + n * 16 + lr;
        Fbf[(size_t)grow * NC + col] = (bf16)(acc[m][n][r] * inv);
      }
    }
}

// ---------------------------------------------------------------------------
extern "C" void kernel_launch(void* const* d_in, const int* in_sizes, int n_in,
                              void* d_out, int out_size, void* d_ws, size_t ws_size,
                              hipStream_t stream) {
  const float* X   = (const float*)d_in[0];
  const int*   lab = (const int*)d_in[1];
  const float* W1  = (const float*)d_in[2];
  const float* W2  = (const float*)d_in[3];
  const float* txt = (const float*)d_in[4];
  const float* lsc = (const float*)d_in[5];
  float* out = (float*)d_out;

  char* ws = (char*)d_ws;
  constexpr size_t SZ_XBF = (size_t)NB * NC * 2;
  constexpr size_t SZ_W1T = (size_t)ND * NH * NC * 2;
  constexpr size_t SZ_W2T = (size_t)ND * NC * NH * 2;
  constexpr size_t SZ_HP  = (size_t)NPMAX * NH * 2;
  constexpr size_t SZ_TBF = (size_t)NTP * NC * 2;
  constexpr size_t SZ_FBF = (size_t)NB * NC * 2;
  constexpr size_t SZ_MAP = (size_t)NPMAX * 4;
  bf16* Xbf = (bf16*)(ws);
  bf16* W1t = (bf16*)(ws + SZ_XBF);
  bf16* W2t = (bf16*)(ws + SZ_XBF + SZ_W1T);
  bf16* Hp  = (bf16*)(ws + SZ_XBF + SZ_W1T + SZ_W2T);
  bf16* Tbf = (bf16*)(ws + SZ_XBF + SZ_W1T + SZ_W2T + SZ_HP);
  bf16* Fbf = (bf16*)(ws + SZ_XBF + SZ_W1T + SZ_W2T + SZ_HP + SZ_TBF);
  int*  map = (int*)(ws + SZ_XBF + SZ_W1T + SZ_W2T + SZ_HP + SZ_TBF + SZ_FBF);
  int*  dmeta = (int*)(ws + SZ_XBF + SZ_W1T + SZ_W2T + SZ_HP + SZ_TBF + SZ_FBF + SZ_MAP);

  k_prep<<<NTP + 96 + 2048, 64, 0, stream>>>(X, W1, W2, txt,
                                             Xbf, W1t, W2t, Tbf);
  k_sort<<<1, 1024, 0, stream>>>(lab, map, dmeta);
  k_gemm1<<<2 * NTILE, 256, 0, stream>>>(Xbf, W1t, map, dmeta, Hp);
  k_gemm2<<<2 * NTILE, 512, 0, stream>>>(Hp, W2t, Xbf, map, dmeta, Fbf);
  k_gemm3<<<dim3(NB / 256, NTP / 128), 512, 0, stream>>>(Fbf, Tbf, lsc, out);
}

// Round 9
// 97.620 us; speedup vs baseline: 1.2557x; 1.2557x over previous
//
#include <hip/hip_runtime.h>
#include <math.h>

typedef __bf16 bf16;
typedef __attribute__((ext_vector_type(8))) __bf16 bf16x8;
typedef __attribute__((ext_vector_type(4))) __bf16 bf16x4;
typedef __attribute__((ext_vector_type(4))) float f32x4;

#define MFMA(a, b, c) __builtin_amdgcn_mfma_f32_16x16x32_bf16((a), (b), (c), 0, 0, 0)
#define BARR() __builtin_amdgcn_s_barrier()
#define SFEN() __builtin_amdgcn_sched_barrier(0)
#define WAITV(n) asm volatile("s_waitcnt vmcnt(" #n ")" ::: "memory")

static constexpr int NB = 16384;   // batch
static constexpr int NC = 512;     // feature dim
static constexpr int NH = 128;     // bottleneck
static constexpr int ND = 3;       // domains
static constexpr int NT = 1380;    // text rows
static constexpr int NTP = 1408;   // padded to 128
static constexpr int NTILE = 131;  // max 128-row packed tiles
static constexpr int NPMAX = NTILE * 128;

__device__ __forceinline__ void gld16(const bf16* g, void* l) {
  __builtin_amdgcn_global_load_lds(
      (const __attribute__((address_space(1))) void*)g,
      (__attribute__((address_space(3))) void*)l, 16, 0, 0);
}

// ---------------------------------------------------------------------------
// prep (R8 version): text row-normalize -> bf16; W1/W2 coalesced LDS-tile
// transpose; X f32 -> bf16.
// ---------------------------------------------------------------------------
__global__ __launch_bounds__(64) void k_prep(
    const float* __restrict__ X, const float* __restrict__ W1,
    const float* __restrict__ W2, const float* __restrict__ txt,
    bf16* __restrict__ Xbf, bf16* __restrict__ W1t,
    bf16* __restrict__ W2t, bf16* __restrict__ Tbf)
{
  __shared__ float tl[64][65];
  const int b = blockIdx.x, t = threadIdx.x;
  if (b < NTP) {
    bf16x4* dst = (bf16x4*)(Tbf + (size_t)b * NC);
    if (b < NT) {
      const float4* src = (const float4*)(txt + (size_t)b * NC);
      float4 u0 = src[t * 2], u1 = src[t * 2 + 1];
      float ssq = u0.x * u0.x + u0.y * u0.y + u0.z * u0.z + u0.w * u0.w +
                  u1.x * u1.x + u1.y * u1.y + u1.z * u1.z + u1.w * u1.w;
      for (int m = 32; m; m >>= 1) ssq += __shfl_xor(ssq, m, 64);
      float inv = 1.0f / sqrtf(ssq);
      bf16x4 o0 = {(bf16)(u0.x * inv), (bf16)(u0.y * inv), (bf16)(u0.z * inv), (bf16)(u0.w * inv)};
      bf16x4 o1 = {(bf16)(u1.x * inv), (bf16)(u1.y * inv), (bf16)(u1.z * inv), (bf16)(u1.w * inv)};
      dst[t * 2] = o0; dst[t * 2 + 1] = o1;
    } else {
      bf16x4 z = {(bf16)0.f, (bf16)0.f, (bf16)0.f, (bf16)0.f};
      dst[t * 2] = z; dst[t * 2 + 1] = z;
    }
  } else if (b < NTP + 48) {
    const int e = b - NTP, d = e >> 4, rem = e & 15;
    const int i0 = (rem >> 1) * 64, n0 = (rem & 1) * 64;
    const float* src = W1 + (size_t)d * NC * NH;
    for (int r = 0; r < 64; ++r) tl[r][t] = src[(size_t)(i0 + r) * NH + n0 + t];
    __syncthreads();
    bf16* dst = W1t + (size_t)d * NH * NC;
    for (int r = 0; r < 64; ++r)
      dst[(size_t)(n0 + r) * NC + i0 + t] = (bf16)tl[t][r];
  } else if (b < NTP + 96) {
    const int e = b - (NTP + 48), d = e >> 4, rem = e & 15;
    const int j0 = (rem >> 3) * 64, n0 = (rem & 7) * 64;
    const float* src = W2 + (size_t)d * NH * NC;
    for (int r = 0; r < 64; ++r) tl[r][t] = src[(size_t)(j0 + r) * NC + n0 + t];
    __syncthreads();
    bf16* dst = W2t + (size_t)d * NC * NH;
    for (int r = 0; r < 64; ++r)
      dst[(size_t)(n0 + r) * NH + j0 + t] = (bf16)tl[t][r];
  } else {
    const int id = b - (NTP + 96);
    const float4* src = (const float4*)X;
    bf16x4* dst = (bf16x4*)Xbf;
    const size_t base = (size_t)id * 1024 + (size_t)t * 16;
    for (int i = 0; i < 16; ++i) {
      float4 u = src[base + i];
      bf16x4 o = {(bf16)u.x, (bf16)u.y, (bf16)u.z, (bf16)u.w};
      dst[base + i] = o;
    }
  }
}

// ---------------------------------------------------------------------------
// k_sort: deterministic counting sort of rows by domain into padded,
// 128-aligned segments. One block, 1024 threads, 16 rows/thread.
// ---------------------------------------------------------------------------
__global__ __launch_bounds__(1024) void k_sort(
    const int* __restrict__ lab, int* __restrict__ map, int* __restrict__ dmeta)
{
  __shared__ int woff[16][3];
  __shared__ int segbase[4];
  __shared__ int padded[3];
  const int t = threadIdx.x, lane = t & 63, wv = t >> 6;
  int c[3] = {0, 0, 0};
  int ld[16];
  const int base = t * 16;
#pragma unroll
  for (int i = 0; i < 16; ++i) { ld[i] = lab[base + i]; c[ld[i]]++; }
  int exc[3];
#pragma unroll
  for (int d = 0; d < 3; ++d) {
    int v = c[d];
    for (int off = 1; off < 64; off <<= 1) {
      int u = __shfl_up(v, off, 64);
      if (lane >= off) v += u;
    }
    exc[d] = v - c[d];
    if (lane == 63) woff[wv][d] = v;
  }
  __syncthreads();
  if (t == 0) {
    int tot[3] = {0, 0, 0};
    for (int w = 0; w < 16; ++w)
      for (int d = 0; d < 3; ++d) { int v = woff[w][d]; woff[w][d] = tot[d]; tot[d] += v; }
    int s = 0;
    for (int d = 0; d < 3; ++d) {
      padded[d] = (tot[d] + 127) & ~127;
      segbase[d] = s; s += padded[d];
    }
    segbase[3] = s;
    dmeta[NTILE] = s;
  }
  __syncthreads();
  for (int tile = t; tile < NTILE; tile += 1024) {
    const int slot = tile * 128;
    int dd = -1;
    for (int d = 0; d < 3; ++d)
      if (slot >= segbase[d] && slot < segbase[d] + padded[d]) dd = d;
    dmeta[tile] = dd;
  }
  for (int i = t; i < NPMAX; i += 1024) map[i] = -1;
  __syncthreads();
  int pos[3];
#pragma unroll
  for (int d = 0; d < 3; ++d) pos[d] = segbase[d] + woff[wv][d] + exc[d];
#pragma unroll
  for (int i = 0; i < 16; ++i) { int d = ld[i]; map[pos[d]++] = base + i; }
}

// ---------------------------------------------------------------------------
// k_adapter (FUSED gemm1+gemm2): per 64-row packed tile:
//   L1: H = relu(X[map] @ W1[d])  (X staged/gathered to LDS, W1 frags from L2)
//   H -> swizzled LDS (16 KiB)
//   L2: F = norm(0.2*relu(H @ W2[d]) + 0.8*X[map]), scatter to Fbf[map]
// grid 2*NTILE x 512 (8 waves). Wave w: L1 col-strip w*16; L2 col-strip w*64.
// ---------------------------------------------------------------------------
__global__ __launch_bounds__(512) void k_adapter(
    const bf16* __restrict__ Xbf, const bf16* __restrict__ W1t,
    const bf16* __restrict__ W2t, const int* __restrict__ map,
    const int* __restrict__ dmeta, bf16* __restrict__ Fbf)
{
  __shared__ bf16 As[2][64 * 64];   // X k-tile, 128 B rows, swizzled
  __shared__ bf16 Hs[64 * 128];     // H, 256 B rows, swizzled
  __shared__ float rssq[8][64];
  __shared__ int smap[64];
  const int bx = blockIdx.x;
  const int d = dmeta[bx >> 1];
  if (d < 0) return;                 // block-uniform, before any barrier
  const int t = threadIdx.x, w = t >> 6, l = t & 63;
  const int lr = l & 15, lg = l >> 4;
  const int row0 = bx * 64;
  if (t < 64) smap[t] = map[row0 + t];

  // ---- staging geometry: 512 thr x 16 B = one 64x64 bf16 tile ----
  int arow = map[row0 + (t >> 3)]; if (arow < 0) arow = 0;
  const int scolb = ((t & 7) * 16) ^ (((t >> 3) & 7) << 4);   // swizzled src byte
#define STGA(buf, kt)                                                        \
  gld16(Xbf + (size_t)arow * NC + (kt) * 64 + (scolb >> 1),                  \
        (char*)As[buf] + t * 16);

  // ---- L1: H strip (64 rows x 16 cols per wave), K=512, BK=64 ----
  f32x4 acc1[4] = {};
  const bf16* W1B = W1t + (size_t)d * NH * NC + (size_t)(w * 16 + lr) * NC;
  STGA(0, 0); STGA(1, 1);
#pragma unroll 1
  for (int kt = 0; kt < 8; ++kt) {
    const int cur = kt & 1;
    if (kt == 7) { WAITV(0); } else { WAITV(1); }
    BARR(); SFEN();
#pragma unroll
    for (int h = 0; h < 2; ++h) {
      bf16x8 a[4];
#pragma unroll
      for (int m = 0; m < 4; ++m) {
        const int r = m * 16 + lr;
        a[m] = *(const bf16x8*)((const char*)As[cur] +
                                r * 128 + ((h * 64 + lg * 16) ^ ((r & 7) << 4)));
      }
      const bf16x8 bq = *(const bf16x8*)(W1B + kt * 64 + h * 32 + lg * 8);
#pragma unroll
      for (int m = 0; m < 4; ++m) acc1[m] = MFMA(a[m], bq, acc1[m]);
    }
    BARR(); SFEN();
    if (kt + 2 < 8) STGA(cur, kt + 2);
  }
#undef STGA

  // ---- H -> LDS (relu), swizzled 256 B rows ----
#pragma unroll
  for (int m = 0; m < 4; ++m)
#pragma unroll
    for (int r = 0; r < 4; ++r) {
      const int row = m * 16 + lg * 4 + r;
      const int colb = (w * 16 + lr) * 2;
      const float v = acc1[m][r];
      *(bf16*)((char*)Hs + row * 256 + (colb ^ ((row & 7) << 4))) =
          (bf16)(v > 0.f ? v : 0.f);
    }
  __syncthreads();

  // ---- L2: F cols [w*64, w*64+64), K=NH=128 ----
  f32x4 acc[4][4] = {};
  const bf16* W2B = W2t + (size_t)d * NC * NH + (size_t)(w * 64) * NH;
#pragma unroll
  for (int ks = 0; ks < 4; ++ks) {
    bf16x8 a[4], bq[4];
#pragma unroll
    for (int m = 0; m < 4; ++m) {
      const int r = m * 16 + lr;
      a[m] = *(const bf16x8*)((const char*)Hs +
                              r * 256 + ((ks * 64 + lg * 16) ^ ((r & 7) << 4)));
    }
#pragma unroll
    for (int n = 0; n < 4; ++n)
      bq[n] = *(const bf16x8*)(W2B + (size_t)(n * 16 + lr) * NH + ks * 32 + lg * 8);
#pragma unroll
    for (int m = 0; m < 4; ++m)
#pragma unroll
      for (int n = 0; n < 4; ++n)
        acc[m][n] = MFMA(a[m], bq[n], acc[m][n]);
  }

  // ---- relu + blend + row-normalize + scatter (gemm2 epilogue) ----
  const int col0 = w * 64;
#pragma unroll
  for (int m = 0; m < 4; ++m)
#pragma unroll
    for (int r = 0; r < 4; ++r) {
      const int rl = m * 16 + lg * 4 + r;
      const int grow = smap[rl];
      const size_t row = grow < 0 ? 0 : (size_t)grow;
      float part = 0.f;
#pragma unroll
      for (int n = 0; n < 4; ++n) {
        const int col = col0 + n * 16 + lr;
        float v = acc[m][n][r];
        v = v > 0.f ? v : 0.f;
        v = 0.2f * v + 0.8f * (float)Xbf[row * NC + col];
        acc[m][n][r] = v;
        part += v * v;
      }
      part += __shfl_xor(part, 1, 64);
      part += __shfl_xor(part, 2, 64);
      part += __shfl_xor(part, 4, 64);
      part += __shfl_xor(part, 8, 64);
      if (lr == 0) rssq[w][rl] = part;
    }
  __syncthreads();
#pragma unroll
  for (int m = 0; m < 4; ++m)
#pragma unroll
    for (int r = 0; r < 4; ++r) {
      const int rl = m * 16 + lg * 4 + r;
      const int grow = smap[rl];
      if (grow < 0) continue;
      float tot = 0.f;
#pragma unroll
      for (int ww = 0; ww < 8; ++ww) tot += rssq[ww][rl];
      const float inv = 1.0f / sqrtf(tot);
#pragma unroll
      for (int n = 0; n < 4; ++n) {
        const int col = col0 + n * 16 + lr;
        Fbf[(size_t)grow * NC + col] = (bf16)(acc[m][n][r] * inv);
      }
    }
}

// ---------------------------------------------------------------------------
// gemm3 (R4-proven variant, 51.7 us, 0 bank conflicts): 128x128 tile, BK=32,
// 256 thr, double-buffered sync-drain, swizzled staging.
// ---------------------------------------------------------------------------
__global__ __launch_bounds__(256) void k_gemm3(
    const bf16* __restrict__ Fbf, const bf16* __restrict__ Tbf,
    const float* __restrict__ lsc, float* __restrict__ out)
{
  __shared__ bf16 As[2][128 * 32];
  __shared__ bf16 Bs[2][128 * 32];
  const int bx = blockIdx.x, by = blockIdx.y;
  const int t = threadIdx.x, w = t >> 6, l = t & 63;
  const int wr = w >> 1, wc = w & 1;
  const int lr = l & 15, lg = l >> 4;
  const int row0 = bx * 128, col0 = by * 128;
  const bf16* Ag = Fbf + (size_t)row0 * NC;
  const bf16* Bg = Tbf + (size_t)col0 * NC;

#define STG3(buf, kt)                                                         \
  {                                                                           \
    _Pragma("unroll")                                                         \
    for (int i = 0; i < 2; ++i) {                                             \
      const int off = (i * 256 + t) * 16;                                     \
      const int row = off >> 6;                                               \
      const int src = (off & 63) ^ (((row >> 1) & 3) << 4);                   \
      const size_t go = (size_t)row * NC + (size_t)(kt) * 32 + (src >> 1);    \
      gld16(Ag + go, (char*)As[buf] + off);                                   \
      gld16(Bg + go, (char*)Bs[buf] + off);                                   \
    }                                                                         \
  }

  f32x4 acc[4][4] = {};
  STG3(0, 0);
#pragma unroll 1
  for (int ks = 0; ks < 16; ++ks) {
    const int cur = ks & 1;
    __syncthreads();
    if (ks + 1 < 16) STG3(cur ^ 1, ks + 1);
    bf16x8 a[4], b[4];
#pragma unroll
    for (int m = 0; m < 4; ++m) {
      const int r = wr * 64 + m * 16 + lr;
      a[m] = *(const bf16x8*)&As[cur][r * 32 + ((lg * 8) ^ (((r >> 1) & 3) << 3))];
    }
#pragma unroll
    for (int n = 0; n < 4; ++n) {
      const int r = wc * 64 + n * 16 + lr;
      b[n] = *(const bf16x8*)&Bs[cur][r * 32 + ((lg * 8) ^ (((r >> 1) & 3) << 3))];
    }
#pragma unroll
    for (int m = 0; m < 4; ++m)
#pragma unroll
      for (int n = 0; n < 4; ++n)
        acc[m][n] = MFMA(a[m], b[n], acc[m][n]);
  }

  const float s = expf(lsc[0]);
#pragma unroll
  for (int m = 0; m < 4; ++m)
#pragma unroll
    for (int n = 0; n < 4; ++n)
#pragma unroll
      for (int r = 0; r < 4; ++r) {
        const int row = row0 + wr * 64 + m * 16 + lg * 4 + r;
        const int col = col0 + wc * 64 + n * 16 + lr;
        if (col < NT) out[(size_t)row * NT + col] = s * acc[m][n][r];
      }
#undef STG3
}

// ---------------------------------------------------------------------------
extern "C" void kernel_launch(void* const* d_in, const int* in_sizes, int n_in,
                              void* d_out, int out_size, void* d_ws, size_t ws_size,
                              hipStream_t stream) {
  const float* X   = (const float*)d_in[0];
  const int*   lab = (const int*)d_in[1];
  const float* W1  = (const float*)d_in[2];
  const float* W2  = (const float*)d_in[3];
  const float* txt = (const float*)d_in[4];
  const float* lsc = (const float*)d_in[5];
  float* out = (float*)d_out;

  char* ws = (char*)d_ws;
  constexpr size_t SZ_XBF = (size_t)NB * NC * 2;
  constexpr size_t SZ_W1T = (size_t)ND * NH * NC * 2;
  constexpr size_t SZ_W2T = (size_t)ND * NC * NH * 2;
  constexpr size_t SZ_TBF = (size_t)NTP * NC * 2;
  constexpr size_t SZ_FBF = (size_t)NB * NC * 2;
  constexpr size_t SZ_MAP = (size_t)NPMAX * 4;
  bf16* Xbf = (bf16*)(ws);
  bf16* W1t = (bf16*)(ws + SZ_XBF);
  bf16* W2t = (bf16*)(ws + SZ_XBF + SZ_W1T);
  bf16* Tbf = (bf16*)(ws + SZ_XBF + SZ_W1T + SZ_W2T);
  bf16* Fbf = (bf16*)(ws + SZ_XBF + SZ_W1T + SZ_W2T + SZ_TBF);
  int*  map = (int*)(ws + SZ_XBF + SZ_W1T + SZ_W2T + SZ_TBF + SZ_FBF);
  int*  dmeta = (int*)(ws + SZ_XBF + SZ_W1T + SZ_W2T + SZ_TBF + SZ_FBF + SZ_MAP);

  k_prep<<<NTP + 96 + 2048, 64, 0, stream>>>(X, W1, W2, txt,
                                             Xbf, W1t, W2t, Tbf);
  k_sort<<<1, 1024, 0, stream>>>(lab, map, dmeta);
  k_adapter<<<2 * NTILE, 512, 0, stream>>>(Xbf, W1t, W2t, map, dmeta, Fbf);
  k_gemm3<<<dim3(NB / 128, NTP / 128), 256, 0, stream>>>(Fbf, Tbf, lsc, out);
}

// Round 10
// 97.216 us; speedup vs baseline: 1.2610x; 1.0042x over previous
//
#include <hip/hip_runtime.h>
#include <math.h>

typedef __bf16 bf16;
typedef __attribute__((ext_vector_type(8))) __bf16 bf16x8;
typedef __attribute__((ext_vector_type(4))) __bf16 bf16x4;
typedef __attribute__((ext_vector_type(4))) float f32x4;

#define MFMA(a, b, c) __builtin_amdgcn_mfma_f32_16x16x32_bf16((a), (b), (c), 0, 0, 0)
#define BARR() __builtin_amdgcn_s_barrier()
#define SFEN() __builtin_amdgcn_sched_barrier(0)
#define WAITV(n) asm volatile("s_waitcnt vmcnt(" #n ")" ::: "memory")
#define LGKM0() asm volatile("s_waitcnt lgkmcnt(0)" ::: "memory")

static constexpr int NB = 16384;   // batch
static constexpr int NC = 512;     // feature dim
static constexpr int NH = 128;     // bottleneck
static constexpr int ND = 3;       // domains
static constexpr int NT = 1380;    // text rows
static constexpr int NTP = 1408;   // padded to 128
static constexpr int NTILE = 131;  // max 128-row packed tiles
static constexpr int NPMAX = NTILE * 128;

__device__ __forceinline__ void gld16(const bf16* g, void* l) {
  __builtin_amdgcn_global_load_lds(
      (const __attribute__((address_space(1))) void*)g,
      (__attribute__((address_space(3))) void*)l, 16, 0, 0);
}

// ---------------------------------------------------------------------------
// prep (unchanged R8): text row-normalize -> bf16; W1/W2 coalesced LDS-tile
// transpose; X f32 -> bf16.
// ---------------------------------------------------------------------------
__global__ __launch_bounds__(64) void k_prep(
    const float* __restrict__ X, const float* __restrict__ W1,
    const float* __restrict__ W2, const float* __restrict__ txt,
    bf16* __restrict__ Xbf, bf16* __restrict__ W1t,
    bf16* __restrict__ W2t, bf16* __restrict__ Tbf)
{
  __shared__ float tl[64][65];
  const int b = blockIdx.x, t = threadIdx.x;
  if (b < NTP) {
    bf16x4* dst = (bf16x4*)(Tbf + (size_t)b * NC);
    if (b < NT) {
      const float4* src = (const float4*)(txt + (size_t)b * NC);
      float4 u0 = src[t * 2], u1 = src[t * 2 + 1];
      float ssq = u0.x * u0.x + u0.y * u0.y + u0.z * u0.z + u0.w * u0.w +
                  u1.x * u1.x + u1.y * u1.y + u1.z * u1.z + u1.w * u1.w;
      for (int m = 32; m; m >>= 1) ssq += __shfl_xor(ssq, m, 64);
      float inv = 1.0f / sqrtf(ssq);
      bf16x4 o0 = {(bf16)(u0.x * inv), (bf16)(u0.y * inv), (bf16)(u0.z * inv), (bf16)(u0.w * inv)};
      bf16x4 o1 = {(bf16)(u1.x * inv), (bf16)(u1.y * inv), (bf16)(u1.z * inv), (bf16)(u1.w * inv)};
      dst[t * 2] = o0; dst[t * 2 + 1] = o1;
    } else {
      bf16x4 z = {(bf16)0.f, (bf16)0.f, (bf16)0.f, (bf16)0.f};
      dst[t * 2] = z; dst[t * 2 + 1] = z;
    }
  } else if (b < NTP + 48) {
    const int e = b - NTP, d = e >> 4, rem = e & 15;
    const int i0 = (rem >> 1) * 64, n0 = (rem & 1) * 64;
    const float* src = W1 + (size_t)d * NC * NH;
    for (int r = 0; r < 64; ++r) tl[r][t] = src[(size_t)(i0 + r) * NH + n0 + t];
    __syncthreads();
    bf16* dst = W1t + (size_t)d * NH * NC;
    for (int r = 0; r < 64; ++r)
      dst[(size_t)(n0 + r) * NC + i0 + t] = (bf16)tl[t][r];
  } else if (b < NTP + 96) {
    const int e = b - (NTP + 48), d = e >> 4, rem = e & 15;
    const int j0 = (rem >> 3) * 64, n0 = (rem & 7) * 64;
    const float* src = W2 + (size_t)d * NH * NC;
    for (int r = 0; r < 64; ++r) tl[r][t] = src[(size_t)(j0 + r) * NC + n0 + t];
    __syncthreads();
    bf16* dst = W2t + (size_t)d * NC * NH;
    for (int r = 0; r < 64; ++r)
      dst[(size_t)(n0 + r) * NH + j0 + t] = (bf16)tl[t][r];
  } else {
    const int id = b - (NTP + 96);
    const float4* src = (const float4*)X;
    bf16x4* dst = (bf16x4*)Xbf;
    const size_t base = (size_t)id * 1024 + (size_t)t * 16;
    for (int i = 0; i < 16; ++i) {
      float4 u = src[base + i];
      bf16x4 o = {(bf16)u.x, (bf16)u.y, (bf16)u.z, (bf16)u.w};
      dst[base + i] = o;
    }
  }
}

// ---------------------------------------------------------------------------
// k_sort (unchanged): deterministic counting sort into padded 128-aligned
// segments. One block, 1024 threads.
// ---------------------------------------------------------------------------
__global__ __launch_bounds__(1024) void k_sort(
    const int* __restrict__ lab, int* __restrict__ map, int* __restrict__ dmeta)
{
  __shared__ int woff[16][3];
  __shared__ int segbase[4];
  __shared__ int padded[3];
  const int t = threadIdx.x, lane = t & 63, wv = t >> 6;
  int c[3] = {0, 0, 0};
  int ld[16];
  const int base = t * 16;
#pragma unroll
  for (int i = 0; i < 16; ++i) { ld[i] = lab[base + i]; c[ld[i]]++; }
  int exc[3];
#pragma unroll
  for (int d = 0; d < 3; ++d) {
    int v = c[d];
    for (int off = 1; off < 64; off <<= 1) {
      int u = __shfl_up(v, off, 64);
      if (lane >= off) v += u;
    }
    exc[d] = v - c[d];
    if (lane == 63) woff[wv][d] = v;
  }
  __syncthreads();
  if (t == 0) {
    int tot[3] = {0, 0, 0};
    for (int w = 0; w < 16; ++w)
      for (int d = 0; d < 3; ++d) { int v = woff[w][d]; woff[w][d] = tot[d]; tot[d] += v; }
    int s = 0;
    for (int d = 0; d < 3; ++d) {
      padded[d] = (tot[d] + 127) & ~127;
      segbase[d] = s; s += padded[d];
    }
    segbase[3] = s;
    dmeta[NTILE] = s;
  }
  __syncthreads();
  for (int tile = t; tile < NTILE; tile += 1024) {
    const int slot = tile * 128;
    int dd = -1;
    for (int d = 0; d < 3; ++d)
      if (slot >= segbase[d] && slot < segbase[d] + padded[d]) dd = d;
    dmeta[tile] = dd;
  }
  for (int i = t; i < NPMAX; i += 1024) map[i] = -1;
  __syncthreads();
  int pos[3];
#pragma unroll
  for (int d = 0; d < 3; ++d) pos[d] = segbase[d] + woff[wv][d] + exc[d];
#pragma unroll
  for (int i = 0; i < 16; ++i) { int d = ld[i]; map[pos[d]++] = base + i; }
}

// ---------------------------------------------------------------------------
// k_adapter (unchanged R9 winner): fused gemm1+gemm2 per 64-row packed tile.
// ---------------------------------------------------------------------------
__global__ __launch_bounds__(512) void k_adapter(
    const bf16* __restrict__ Xbf, const bf16* __restrict__ W1t,
    const bf16* __restrict__ W2t, const int* __restrict__ map,
    const int* __restrict__ dmeta, bf16* __restrict__ Fbf)
{
  __shared__ bf16 As[2][64 * 64];
  __shared__ bf16 Hs[64 * 128];
  __shared__ float rssq[8][64];
  __shared__ int smap[64];
  const int bx = blockIdx.x;
  const int d = dmeta[bx >> 1];
  if (d < 0) return;
  const int t = threadIdx.x, w = t >> 6, l = t & 63;
  const int lr = l & 15, lg = l >> 4;
  const int row0 = bx * 64;
  if (t < 64) smap[t] = map[row0 + t];

  int arow = map[row0 + (t >> 3)]; if (arow < 0) arow = 0;
  const int scolb = ((t & 7) * 16) ^ (((t >> 3) & 7) << 4);
#define STGA(buf, kt)                                                        \
  gld16(Xbf + (size_t)arow * NC + (kt) * 64 + (scolb >> 1),                  \
        (char*)As[buf] + t * 16);

  f32x4 acc1[4] = {};
  const bf16* W1B = W1t + (size_t)d * NH * NC + (size_t)(w * 16 + lr) * NC;
  STGA(0, 0); STGA(1, 1);
#pragma unroll 1
  for (int kt = 0; kt < 8; ++kt) {
    const int cur = kt & 1;
    if (kt == 7) { WAITV(0); } else { WAITV(1); }
    BARR(); SFEN();
#pragma unroll
    for (int h = 0; h < 2; ++h) {
      bf16x8 a[4];
#pragma unroll
      for (int m = 0; m < 4; ++m) {
        const int r = m * 16 + lr;
        a[m] = *(const bf16x8*)((const char*)As[cur] +
                                r * 128 + ((h * 64 + lg * 16) ^ ((r & 7) << 4)));
      }
      const bf16x8 bq = *(const bf16x8*)(W1B + kt * 64 + h * 32 + lg * 8);
#pragma unroll
      for (int m = 0; m < 4; ++m) acc1[m] = MFMA(a[m], bq, acc1[m]);
    }
    BARR(); SFEN();
    if (kt + 2 < 8) STGA(cur, kt + 2);
  }
#undef STGA

#pragma unroll
  for (int m = 0; m < 4; ++m)
#pragma unroll
    for (int r = 0; r < 4; ++r) {
      const int row = m * 16 + lg * 4 + r;
      const int colb = (w * 16 + lr) * 2;
      const float v = acc1[m][r];
      *(bf16*)((char*)Hs + row * 256 + (colb ^ ((row & 7) << 4))) =
          (bf16)(v > 0.f ? v : 0.f);
    }
  __syncthreads();

  f32x4 acc[4][4] = {};
  const bf16* W2B = W2t + (size_t)d * NC * NH + (size_t)(w * 64) * NH;
#pragma unroll
  for (int ks = 0; ks < 4; ++ks) {
    bf16x8 a[4], bq[4];
#pragma unroll
    for (int m = 0; m < 4; ++m) {
      const int r = m * 16 + lr;
      a[m] = *(const bf16x8*)((const char*)Hs +
                              r * 256 + ((ks * 64 + lg * 16) ^ ((r & 7) << 4)));
    }
#pragma unroll
    for (int n = 0; n < 4; ++n)
      bq[n] = *(const bf16x8*)(W2B + (size_t)(n * 16 + lr) * NH + ks * 32 + lg * 8);
#pragma unroll
    for (int m = 0; m < 4; ++m)
#pragma unroll
      for (int n = 0; n < 4; ++n)
        acc[m][n] = MFMA(a[m], bq[n], acc[m][n]);
  }

  const int col0 = w * 64;
#pragma unroll
  for (int m = 0; m < 4; ++m)
#pragma unroll
    for (int r = 0; r < 4; ++r) {
      const int rl = m * 16 + lg * 4 + r;
      const int grow = smap[rl];
      const size_t row = grow < 0 ? 0 : (size_t)grow;
      float part = 0.f;
#pragma unroll
      for (int n = 0; n < 4; ++n) {
        const int col = col0 + n * 16 + lr;
        float v = acc[m][n][r];
        v = v > 0.f ? v : 0.f;
        v = 0.2f * v + 0.8f * (float)Xbf[row * NC + col];
        acc[m][n][r] = v;
        part += v * v;
      }
      part += __shfl_xor(part, 1, 64);
      part += __shfl_xor(part, 2, 64);
      part += __shfl_xor(part, 4, 64);
      part += __shfl_xor(part, 8, 64);
      if (lr == 0) rssq[w][rl] = part;
    }
  __syncthreads();
#pragma unroll
  for (int m = 0; m < 4; ++m)
#pragma unroll
    for (int r = 0; r < 4; ++r) {
      const int rl = m * 16 + lg * 4 + r;
      const int grow = smap[rl];
      if (grow < 0) continue;
      float tot = 0.f;
#pragma unroll
      for (int ww = 0; ww < 8; ++ww) tot += rssq[ww][rl];
      const float inv = 1.0f / sqrtf(tot);
#pragma unroll
      for (int n = 0; n < 4; ++n) {
        const int col = col0 + n * 16 + lr;
        Fbf[(size_t)grow * NC + col] = (bf16)(acc[m][n][r] * inv);
      }
    }
}

// ---------------------------------------------------------------------------
// gemm3 (NEW: counted-vmcnt phase-split pipeline, T3+T4 port):
// 128x128 tile, 4 waves, BK=64, 2 buffers (64 KiB -> 2 blocks/CU), 8 K-tiles.
// Steady state: WAITV(8) keeps tile k+1's 8 loads in flight across barriers
// (never drains to 0 in the loop). Per K-tile: 2 phases (K-slice 0/1), each
// {8x ds_read_b128; lgkmcnt(0); 16 MFMA}; stage of tile k+2 issued after the
// phase-B barrier certifying all waves finished reading buffer c.
// Swizzle: byte ^= (row&7)<<4 on 128-B rows (2 lanes/bank, conflict-free).
// ---------------------------------------------------------------------------
__global__ __launch_bounds__(256) void k_gemm3(
    const bf16* __restrict__ Fbf, const bf16* __restrict__ Tbf,
    const float* __restrict__ lsc, float* __restrict__ out)
{
  __shared__ bf16 As[2][128 * 64];
  __shared__ bf16 Bs[2][128 * 64];
  const int bx = blockIdx.x, by = blockIdx.y;
  const int t = threadIdx.x, w = t >> 6, l = t & 63;
  const int wr = w >> 1, wc = w & 1;
  const int lr = l & 15, lg = l >> 4;
  const int row0 = bx * 128, col0 = by * 128;
  const bf16* Ag = Fbf + (size_t)row0 * NC;
  const bf16* Bg = Tbf + (size_t)col0 * NC;

  // staging geometry: 16 KB per matrix per K-tile = 256 thr x 4 x 16 B
  int srow[4], scol[4];
#pragma unroll
  for (int i = 0; i < 4; ++i) {
    const int off = (i * 256 + t) * 16;
    srow[i] = off >> 7;                                   // 128 B rows
    scol[i] = ((off & 127) ^ ((srow[i] & 7) << 4)) >> 1;  // pre-swizzled src col
  }
#define STG3(buf, kt)                                                         \
  {                                                                           \
    _Pragma("unroll")                                                         \
    for (int i = 0; i < 4; ++i) {                                             \
      const int off = (i * 256 + t) * 16;                                     \
      gld16(Ag + (size_t)srow[i] * NC + (kt) * 64 + scol[i],                  \
            (char*)As[buf] + off);                                            \
    }                                                                         \
    _Pragma("unroll")                                                         \
    for (int i = 0; i < 4; ++i) {                                             \
      const int off = (i * 256 + t) * 16;                                     \
      gld16(Bg + (size_t)srow[i] * NC + (kt) * 64 + scol[i],                  \
            (char*)Bs[buf] + off);                                            \
    }                                                                         \
  }

  f32x4 acc[4][4] = {};
  STG3(0, 0); STG3(1, 1);                      // 16 outstanding (8 per tile)
#pragma unroll 1
  for (int k = 0; k < 8; ++k) {
    const int c = k & 1;
    if (k < 7) { WAITV(8); } else { WAITV(0); }   // tile k fully landed (FIFO)
    BARR(); SFEN();                               // ...for ALL waves
    const char* Ab = (const char*)As[c];
    const char* Bb = (const char*)Bs[c];
    // ---- phase A: K-slice 0 ----
    {
      bf16x8 a[4], b[4];
#pragma unroll
      for (int m = 0; m < 4; ++m) {
        const int r = wr * 64 + m * 16 + lr;
        a[m] = *(const bf16x8*)(Ab + r * 128 + ((lg * 16) ^ ((r & 7) << 4)));
      }
#pragma unroll
      for (int n = 0; n < 4; ++n) {
        const int r = wc * 64 + n * 16 + lr;
        b[n] = *(const bf16x8*)(Bb + r * 128 + ((lg * 16) ^ ((r & 7) << 4)));
      }
      LGKM0(); SFEN();
      __builtin_amdgcn_s_setprio(1);
#pragma unroll
      for (int m = 0; m < 4; ++m)
#pragma unroll
        for (int n = 0; n < 4; ++n)
          acc[m][n] = MFMA(a[m], b[n], acc[m][n]);
      __builtin_amdgcn_s_setprio(0);
    }
    // ---- phase B: K-slice 1; then free buffer c and restage ----
    {
      bf16x8 a[4], b[4];
#pragma unroll
      for (int m = 0; m < 4; ++m) {
        const int r = wr * 64 + m * 16 + lr;
        a[m] = *(const bf16x8*)(Ab + r * 128 + ((64 + lg * 16) ^ ((r & 7) << 4)));
      }
#pragma unroll
      for (int n = 0; n < 4; ++n) {
        const int r = wc * 64 + n * 16 + lr;
        b[n] = *(const bf16x8*)(Bb + r * 128 + ((64 + lg * 16) ^ ((r & 7) << 4)));
      }
      LGKM0(); SFEN();
      BARR(); SFEN();                      // all waves done reading buf c
      if (k + 2 < 8) STG3(c, k + 2);       // restage freed buffer
      __builtin_amdgcn_s_setprio(1);
#pragma unroll
      for (int m = 0; m < 4; ++m)
#pragma unroll
        for (int n = 0; n < 4; ++n)
          acc[m][n] = MFMA(a[m], b[n], acc[m][n]);
      __builtin_amdgcn_s_setprio(0);
    }
  }

  const float s = expf(lsc[0]);
#pragma unroll
  for (int m = 0; m < 4; ++m)
#pragma unroll
    for (int n = 0; n < 4; ++n)
#pragma unroll
      for (int r = 0; r < 4; ++r) {
        const int row = row0 + wr * 64 + m * 16 + lg * 4 + r;
        const int col = col0 + wc * 64 + n * 16 + lr;
        if (col < NT) out[(size_t)row * NT + col] = s * acc[m][n][r];
      }
#undef STG3
}

// ---------------------------------------------------------------------------
extern "C" void kernel_launch(void* const* d_in, const int* in_sizes, int n_in,
                              void* d_out, int out_size, void* d_ws, size_t ws_size,
                              hipStream_t stream) {
  const float* X   = (const float*)d_in[0];
  const int*   lab = (const int*)d_in[1];
  const float* W1  = (const float*)d_in[2];
  const float* W2  = (const float*)d_in[3];
  const float* txt = (const float*)d_in[4];
  const float* lsc = (const float*)d_in[5];
  float* out = (float*)d_out;

  char* ws = (char*)d_ws;
  constexpr size_t SZ_XBF = (size_t)NB * NC * 2;
  constexpr size_t SZ_W1T = (size_t)ND * NH * NC * 2;
  constexpr size_t SZ_W2T = (size_t)ND * NC * NH * 2;
  constexpr size_t SZ_TBF = (size_t)NTP * NC * 2;
  constexpr size_t SZ_FBF = (size_t)NB * NC * 2;
  constexpr size_t SZ_MAP = (size_t)NPMAX * 4;
  bf16* Xbf = (bf16*)(ws);
  bf16* W1t = (bf16*)(ws + SZ_XBF);
  bf16* W2t = (bf16*)(ws + SZ_XBF + SZ_W1T);
  bf16* Tbf = (bf16*)(ws + SZ_XBF + SZ_W1T + SZ_W2T);
  bf16* Fbf = (bf16*)(ws + SZ_XBF + SZ_W1T + SZ_W2T + SZ_TBF);
  int*  map = (int*)(ws + SZ_XBF + SZ_W1T + SZ_W2T + SZ_TBF + SZ_FBF);
  int*  dmeta = (int*)(ws + SZ_XBF + SZ_W1T + SZ_W2T + SZ_TBF + SZ_FBF + SZ_MAP);

  k_prep<<<NTP + 96 + 2048, 64, 0, stream>>>(X, W1, W2, txt,
                                             Xbf, W1t, W2t, Tbf);
  k_sort<<<1, 1024, 0, stream>>>(lab, map, dmeta);
  k_adapter<<<2 * NTILE, 512, 0, stream>>>(Xbf, W1t, W2t, map, dmeta, Fbf);
  k_gemm3<<<dim3(NB / 128, NTP / 128), 256, 0, stream>>>(Fbf, Tbf, lsc, out);
}